// Round 3
// baseline (400.750 us; speedup 1.0000x reference)
//
#include <hip/hip_runtime.h>
#include <math.h>

namespace {
constexpr int WV = 256;               // volume W=H=D
constexpr int NCOL = 384, NROW = 64, NVIEW = 16, NSAMP = 256;
constexpr float DET_U = 1.2f, DET_V = 1.2f;
constexpr float ISO = 500.0f, SDD = 1000.0f;
constexpr double SQRT3 = 1.7320508075688772;
constexpr float DT = (float)SQRT3;                          // RAY_LEN / NSAMP
constexpr float T0 = (float)(500.0 - SQRT3 * 256.0 * 0.5); // ISO - RAY_LEN/2
}

__global__ __launch_bounds__(256) void projector3d_kernel(
    const float* __restrict__ vol,     // [256][256][256], z-major
    const float* __restrict__ angles,  // [16]
    float* __restrict__ out)           // [16][64][384]
{
    const int tid = blockIdx.x * blockDim.x + threadIdx.x;
    const int col = tid % NCOL;
    const int rv  = tid / NCOL;
    const int row = rv % NROW;
    const int view = rv / NROW;

    const float beta = angles[view];
    const float cb = cosf(beta), sb = sinf(beta);
    const float u = (col - NCOL * 0.5f + 0.5f) * DET_U;
    const float v = (row - NROW * 0.5f + 0.5f) * DET_V;

    // source and detector point (z of source = 0)
    const float sx = ISO * cb, sy = ISO * sb;
    const float detx = -(SDD - ISO) * cb - u * sb;
    const float dety = -(SDD - ISO) * sb + u * cb;
    const float detz = v;

    float dx = detx - sx, dy = dety - sy, dz = detz;
    const float inv = 1.0f / sqrtf(dx * dx + dy * dy + dz * dz);
    dx *= inv; dy *= inv; dz *= inv;

    float acc = 0.0f;
    #pragma unroll 4
    for (int s = 0; s < NSAMP; ++s) {
        const float t = T0 + (s + 0.5f) * DT;
        const float vx = fmaf(t, dx, sx) + 127.5f;   // PIX = 1
        const float vy = fmaf(t, dy, sy) + 127.5f;
        const float vz = t * dz + 127.5f;            // src z = 0

        const float fx0 = floorf(vx), fy0 = floorf(vy), fz0 = floorf(vz);
        const int x0 = (int)fx0, y0 = (int)fy0, z0 = (int)fz0;
        const float fx = vx - fx0, fy = vy - fy0, fz = vz - fz0;

        if ((unsigned)x0 < 255u && (unsigned)y0 < 255u && (unsigned)z0 < 255u) {
            // fast path: full 2x2x2 cell interior
            const float* p = vol + ((z0 << 16) | (y0 << 8) | x0);
            const float v000 = p[0],       v001 = p[1];
            const float v010 = p[256],     v011 = p[257];
            const float v100 = p[65536],   v101 = p[65537];
            const float v110 = p[65792],   v111 = p[65793];
            const float c00 = fmaf(fx, v001 - v000, v000);
            const float c01 = fmaf(fx, v011 - v010, v010);
            const float c10 = fmaf(fx, v101 - v100, v100);
            const float c11 = fmaf(fx, v111 - v110, v110);
            const float c0 = fmaf(fy, c01 - c00, c00);
            const float c1 = fmaf(fy, c11 - c10, c10);
            acc += fmaf(fz, c1 - c0, c0);
        } else if (vx > -1.0f && vx < 256.0f &&
                   vy > -1.0f && vy < 256.0f &&
                   vz > -1.0f && vz < 256.0f) {
            // boundary shell: per-corner bounds check (zero outside)
            float sum = 0.0f;
            #pragma unroll
            for (int dzz = 0; dzz < 2; ++dzz) {
                const float wz = dzz ? fz : 1.0f - fz;
                const int zi = z0 + dzz;
                #pragma unroll
                for (int dyy = 0; dyy < 2; ++dyy) {
                    const float wy = dyy ? fy : 1.0f - fy;
                    const int yi = y0 + dyy;
                    #pragma unroll
                    for (int dxx = 0; dxx < 2; ++dxx) {
                        const float wx = dxx ? fx : 1.0f - fx;
                        const int xi = x0 + dxx;
                        if ((unsigned)xi < 256u && (unsigned)yi < 256u &&
                            (unsigned)zi < 256u) {
                            sum += wz * wy * wx * vol[(zi << 16) | (yi << 8) | xi];
                        }
                    }
                }
            }
            acc += sum;
        }
        // fully outside: contributes 0
    }

    out[tid] = acc * DT;
}

extern "C" void kernel_launch(void* const* d_in, const int* in_sizes, int n_in,
                              void* d_out, int out_size, void* d_ws, size_t ws_size,
                              hipStream_t stream) {
    const float* vol    = (const float*)d_in[0];   // image [1,1,256,256,256] fp32
    const float* angles = (const float*)d_in[1];   // [16] fp32
    float* out = (float*)d_out;                    // [1,1,16,64,384] fp32

    const int total = NVIEW * NROW * NCOL;         // 393216
    const int block = 256;
    const int grid = total / block;                // 1536
    projector3d_kernel<<<grid, block, 0, stream>>>(vol, angles, out);
}

// Round 5
// 353.344 us; speedup vs baseline: 1.1342x; 1.1342x over previous
//
#include <hip/hip_runtime.h>
#include <math.h>

namespace {
constexpr int NCOL = 384, NROW = 64, NVIEW = 16, NSAMP = 256;
constexpr float DET_U = 1.2f, DET_V = 1.2f;
constexpr float ISO = 500.0f, SDD = 1000.0f;
constexpr double SQRT3 = 1.7320508075688772;
constexpr float DT = (float)SQRT3;                          // RAY_LEN / NSAMP
constexpr float T0 = (float)(500.0 - SQRT3 * 256.0 * 0.5); // ISO - RAY_LEN/2
}

// t-interval where p0 + t*d lies in [LO, HI]; empty -> [1e30, -1e30]
__device__ __forceinline__ void axis_interval(float p0, float d, float LO, float HI,
                                              float& tlo, float& thi) {
    if (fabsf(d) < 1e-7f) {
        if (p0 < LO || p0 > HI) { tlo = 1e30f; thi = -1e30f; }
        else                    { tlo = -1e30f; thi = 1e30f; }
    } else {
        const float r = 1.0f / d;
        const float t1 = (LO - p0) * r, t2 = (HI - p0) * r;
        tlo = fminf(t1, t2); thi = fmaxf(t1, t2);
    }
}

// general (shell) sample: per-corner bounds check, zero outside
__device__ __forceinline__ float sample_shell(const float* __restrict__ vol,
                                              float vx, float vy, float vz) {
    if (!(vx > -1.0f && vx < 256.0f && vy > -1.0f && vy < 256.0f &&
          vz > -1.0f && vz < 256.0f))
        return 0.0f;
    const float fx0 = floorf(vx), fy0 = floorf(vy), fz0 = floorf(vz);
    const int x0 = (int)fx0, y0 = (int)fy0, z0 = (int)fz0;
    const float fx = vx - fx0, fy = vy - fy0, fz = vz - fz0;
    float sum = 0.0f;
    #pragma unroll
    for (int dzz = 0; dzz < 2; ++dzz) {
        const float wz = dzz ? fz : 1.0f - fz;
        const int zi = z0 + dzz;
        #pragma unroll
        for (int dyy = 0; dyy < 2; ++dyy) {
            const float wy = dyy ? fy : 1.0f - fy;
            const int yi = y0 + dyy;
            #pragma unroll
            for (int dxx = 0; dxx < 2; ++dxx) {
                const float wx = dxx ? fx : 1.0f - fx;
                const int xi = x0 + dxx;
                if ((unsigned)xi < 256u && (unsigned)yi < 256u && (unsigned)zi < 256u)
                    sum += wz * wy * wx * vol[(zi << 16) | (yi << 8) | xi];
            }
        }
    }
    return sum;
}

__global__ __launch_bounds__(256) void projector3d_kernel(
    const float* __restrict__ vol,     // [256][256][256], z-major
    const float* __restrict__ angles,  // [16]
    float* __restrict__ out)           // [16][64][384]
{
    // XCD-aware swizzle: 1536 blocks, 1536 % 8 == 0 -> bijective.
    // Consecutive 192-block chunks (2 full views) land on one XCD -> L2 locality.
    const int nwg = (NVIEW * NROW * NCOL) / 256;   // 1536
    const int cpx = nwg / 8;                       // 192
    const int bid = blockIdx.x;
    const int swz = (bid % 8) * cpx + bid / 8;
    const int tid = swz * 256 + threadIdx.x;

    const int col = tid % NCOL;
    const int rv  = tid / NCOL;
    const int row = rv % NROW;
    const int view = rv / NROW;

    const float beta = angles[view];
    const float cb = cosf(beta), sb = sinf(beta);
    const float u = (col - NCOL * 0.5f + 0.5f) * DET_U;
    const float v = (row - NROW * 0.5f + 0.5f) * DET_V;

    const float sx = ISO * cb, sy = ISO * sb;               // source (z=0)
    const float detx = -(SDD - ISO) * cb - u * sb;
    const float dety = -(SDD - ISO) * sb + u * cb;
    const float detz = v;

    float dx = detx - sx, dy = dety - sy, dz = detz;
    const float inv = 1.0f / sqrtf(dx * dx + dy * dy + dz * dz);
    dx *= inv; dy *= inv; dz *= inv;

    // voxel-space ray: p(t) = b + t*d
    const float bx = sx + 127.5f, by = sy + 127.5f, bz = 127.5f;

    // --- s-intervals ---------------------------------------------------------
    // interior: whole 2x2x2 cell in-bounds (coord in [0.01, 254.99], inward-safe)
    // outer:    any possible contribution (coord in [-1.05, 256.05], outward-safe)
    float xl, xh, yl, yh, zl, zh;
    axis_interval(bx, dx, 0.01f, 254.99f, xl, xh);
    axis_interval(by, dy, 0.01f, 254.99f, yl, yh);
    axis_interval(bz, dz, 0.01f, 254.99f, zl, zh);
    const float tin  = fmaxf(xl, fmaxf(yl, zl));
    const float tout = fminf(xh, fminf(yh, zh));

    axis_interval(bx, dx, -1.05f, 256.05f, xl, xh);
    axis_interval(by, dy, -1.05f, 256.05f, yl, yh);
    axis_interval(bz, dz, -1.05f, 256.05f, zl, zh);
    const float glo = fmaxf(xl, fmaxf(yl, zl));
    const float ghi = fminf(xh, fminf(yh, zh));

    // map t -> sample index s (t_s = T0 + (s+0.5)*DT); clamp floats to [0,256]
    // before int conversion (interval markers are +-1e30).
    const float invdt = 1.0f / DT;
    float g0f = floorf((glo - T0) * invdt - 0.5f);            // outward slop
    float g1f = ceilf((ghi - T0) * invdt - 0.5f) + 1.0f;
    float s0f = ceilf((tin - T0) * invdt - 0.5f + 0.01f);     // inward slop
    float s1f = floorf((tout - T0) * invdt - 0.5f - 0.01f) + 1.0f;
    int g0 = (int)fminf(fmaxf(g0f, 0.0f), 256.0f);
    int g1 = (int)fminf(fmaxf(g1f, 0.0f), 256.0f);
    int s0 = (int)fminf(fmaxf(s0f, 0.0f), 256.0f);
    int s1 = (int)fminf(fmaxf(s1f, 0.0f), 256.0f);
    s0 = max(s0, g0); s1 = min(s1, g1);
    if (s1 < s0) { s0 = g0; s1 = g0; }   // no interior span: all-general

    float acc = 0.0f;

    // shell samples before interior span
    for (int s = g0; s < s0; ++s) {
        const float t = T0 + (s + 0.5f) * DT;
        acc += sample_shell(vol, fmaf(t, dx, bx), fmaf(t, dy, by), fmaf(t, dz, bz));
    }

    // hot loop: branch-free, all 8 corners guaranteed in-bounds
    #pragma unroll 4
    for (int s = s0; s < s1; ++s) {
        const float t = T0 + (s + 0.5f) * DT;
        const float vx = fmaf(t, dx, bx);
        const float vy = fmaf(t, dy, by);
        const float vz = fmaf(t, dz, bz);
        const float fx0 = floorf(vx), fy0 = floorf(vy), fz0 = floorf(vz);
        const int x0 = (int)fx0, y0 = (int)fy0, z0 = (int)fz0;
        const float fx = vx - fx0, fy = vy - fy0, fz = vz - fz0;

        const float* p = vol + ((z0 << 16) | (y0 << 8) | x0);
        const float v000 = p[0],     v001 = p[1];
        const float v010 = p[256],   v011 = p[257];
        const float v100 = p[65536], v101 = p[65537];
        const float v110 = p[65792], v111 = p[65793];
        const float c00 = fmaf(fx, v001 - v000, v000);
        const float c01 = fmaf(fx, v011 - v010, v010);
        const float c10 = fmaf(fx, v101 - v100, v100);
        const float c11 = fmaf(fx, v111 - v110, v110);
        const float c0 = fmaf(fy, c01 - c00, c00);
        const float c1 = fmaf(fy, c11 - c10, c10);
        acc += fmaf(fz, c1 - c0, c0);
    }

    // shell samples after interior span
    for (int s = s1; s < g1; ++s) {
        const float t = T0 + (s + 0.5f) * DT;
        acc += sample_shell(vol, fmaf(t, dx, bx), fmaf(t, dy, by), fmaf(t, dz, bz));
    }

    out[tid] = acc * DT;
}

extern "C" void kernel_launch(void* const* d_in, const int* in_sizes, int n_in,
                              void* d_out, int out_size, void* d_ws, size_t ws_size,
                              hipStream_t stream) {
    const float* vol    = (const float*)d_in[0];   // image [1,1,256,256,256] fp32
    const float* angles = (const float*)d_in[1];   // [16] fp32
    float* out = (float*)d_out;                    // [1,1,16,64,384] fp32

    const int total = NVIEW * NROW * NCOL;         // 393216
    const int block = 256;
    const int grid = total / block;                // 1536
    projector3d_kernel<<<grid, block, 0, stream>>>(vol, angles, out);
}